// Round 1
// baseline (239.209 us; speedup 1.0000x reference)
//
#include <hip/hip_runtime.h>

// MoE gate: logits = x @ W^T, softmax(fp32), top-6 indices (prob order, ties -> lower idx),
// weights = pre-softmax logits gathered at indices (* route_scale = 1.0).
// Outputs concatenated: [T*6] indices (as float), [T*6] weights (float).

constexpr int T_ = 32768;
constexpr int D_ = 2048;
constexpr int E_ = 64;
constexpr int KSEL = 6;
constexpr float ROUTE_SCALE_ = 1.0f;

constexpr int ROWS = 64;          // rows per block
constexpr int DK = 64;            // K chunk staged in LDS
constexpr int NCH = D_ / DK;      // 32 chunks

// XOR swizzles keep ds_read_b128 bank conflicts <=2-way (free) on both tiles.
__device__ __forceinline__ int xsw(int row, int k) {
  return (row * DK + k) ^ ((row & 7) << 2);
}
__device__ __forceinline__ int wsw(int e, int k) {
  return (e * DK + k) ^ (((e >> 2) & 7) << 2);
}

__launch_bounds__(256, 2)
__global__ void gate_kernel(const float* __restrict__ x, const float* __restrict__ W,
                            float* __restrict__ out) {
  __shared__ float xs[ROWS * DK];   // 16 KB, reused as logits tile in epilogue
  __shared__ float ws[E_ * DK];     // 16 KB

  const int tid = threadIdx.x;
  const int eg = tid & 15;          // expert group (4 experts each)
  const int rg = tid >> 4;          // row group (4 rows each)
  const int r0 = blockIdx.x * ROWS;

  float acc[4][4] = {};

  for (int ch = 0; ch < NCH; ++ch) {
    const int c0 = ch * DK;
    __syncthreads();  // previous chunk's LDS reads done before overwrite
    // stage x tile: 64 rows x 64 k = 1024 float4, coalesced (256B per row segment)
#pragma unroll
    for (int s = 0; s < 4; ++s) {
      int f = tid + s * 256;
      int row = f >> 4, c4 = f & 15;
      const float4 v = *reinterpret_cast<const float4*>(
          &x[(size_t)(r0 + row) * D_ + c0 + c4 * 4]);
      *reinterpret_cast<float4*>(&xs[xsw(row, c4 * 4)]) = v;
    }
    // stage W tile: 64 e x 64 k
#pragma unroll
    for (int s = 0; s < 4; ++s) {
      int f = tid + s * 256;
      int e = f >> 4, c4 = f & 15;
      const float4 v = *reinterpret_cast<const float4*>(
          &W[(size_t)e * D_ + c0 + c4 * 4]);
      *reinterpret_cast<float4*>(&ws[wsw(e, c4 * 4)]) = v;
    }
    __syncthreads();
#pragma unroll
    for (int k0 = 0; k0 < DK; k0 += 4) {
      float4 xf[4], wf[4];
#pragma unroll
      for (int i = 0; i < 4; ++i)
        xf[i] = *reinterpret_cast<const float4*>(&xs[xsw(4 * rg + i, k0)]);
#pragma unroll
      for (int j = 0; j < 4; ++j)
        wf[j] = *reinterpret_cast<const float4*>(&ws[wsw(4 * eg + j, k0)]);
#pragma unroll
      for (int i = 0; i < 4; ++i)
#pragma unroll
        for (int j = 0; j < 4; ++j) {
          acc[i][j] = fmaf(xf[i].x, wf[j].x, acc[i][j]);
          acc[i][j] = fmaf(xf[i].y, wf[j].y, acc[i][j]);
          acc[i][j] = fmaf(xf[i].z, wf[j].z, acc[i][j]);
          acc[i][j] = fmaf(xf[i].w, wf[j].w, acc[i][j]);
        }
    }
  }

  // dump logits tile to LDS: xs[row][e]
  __syncthreads();
#pragma unroll
  for (int i = 0; i < 4; ++i) {
    float4 v = make_float4(acc[i][0], acc[i][1], acc[i][2], acc[i][3]);
    *reinterpret_cast<float4*>(&xs[(4 * rg + i) * E_ + 4 * eg]) = v;
  }
  __syncthreads();

  // epilogue: one wave per 16 rows; lane = expert
  const int wave = tid >> 6;
  const int lane = tid & 63;
  float* outI = out;                       // indices as float
  float* outW = out + (size_t)T_ * KSEL;   // weights

  for (int rr = 0; rr < 16; ++rr) {
    const int r = wave * 16 + rr;
    const float lg = xs[r * E_ + lane];
    float m = lg;
#pragma unroll
    for (int off = 32; off; off >>= 1) m = fmaxf(m, __shfl_xor(m, off, 64));
    const float p = expf(lg - m);
    float ssum = p;
#pragma unroll
    for (int off = 32; off; off >>= 1) ssum += __shfl_xor(ssum, off, 64);
    float prob = p / ssum;   // full softmax to match reference top-k semantics

    const int rglob = r0 + r;
#pragma unroll
    for (int kk = 0; kk < KSEL; ++kk) {
      float v = prob;
      int idx = lane;
#pragma unroll
      for (int off = 32; off; off >>= 1) {
        float ov = __shfl_xor(v, off, 64);
        int oi = __shfl_xor(idx, off, 64);
        if (ov > v || (ov == v && oi < idx)) { v = ov; idx = oi; }
      }
      // all lanes agree on (v, idx) after full butterfly
      const float wsel = __shfl(lg, idx, 64);
      if (lane == 0) {
        outI[(size_t)rglob * KSEL + kk] = (float)idx;
        outW[(size_t)rglob * KSEL + kk] = wsel * ROUTE_SCALE_;
      }
      if (lane == idx) prob = -1.0f;  // exclude winner; probs >= 0
    }
  }
}

extern "C" void kernel_launch(void* const* d_in, const int* in_sizes, int n_in,
                              void* d_out, int out_size, void* d_ws, size_t ws_size,
                              hipStream_t stream) {
  const float* x = (const float*)d_in[0];
  const float* W = (const float*)d_in[1];
  float* out = (float*)d_out;
  gate_kernel<<<dim3(T_ / ROWS), dim3(256), 0, stream>>>(x, W, out);
}

// Round 2
// 143.007 us; speedup vs baseline: 1.6727x; 1.6727x over previous
//
#include <hip/hip_runtime.h>

typedef float f32x4 __attribute__((ext_vector_type(4)));
typedef short bf16x8 __attribute__((ext_vector_type(8)));
typedef unsigned short u16;
typedef u16 u16x8 __attribute__((ext_vector_type(8)));

constexpr int T_ = 32768;
constexpr int D_ = 2048;
constexpr int E_ = 64;
constexpr int KSEL = 6;
constexpr float ROUTE_SCALE_ = 1.0f;

constexpr int MB = 64;          // rows per block
constexpr int DK = 64;          // K per chunk
constexpr int NCH = D_ / DK;    // 32

// round-to-nearest-even fp32 -> bf16 bits
__device__ __forceinline__ u16 f2bf(float f) {
  unsigned u = __float_as_uint(f);
  return (u16)((u + 0x7fffu + ((u >> 16) & 1u)) >> 16);
}
__device__ __forceinline__ float bf2f(u16 h) {
  return __uint_as_float(((unsigned)h) << 16);
}
// XOR-swizzled byte offset in a [rows][64] bf16 tile (row stride 128B).
// Breaks the 16-way bank conflict of column reads; residual 2-way = free.
__device__ __forceinline__ int swz(int row, int kb) {
  return row * 128 + (kb ^ ((row & 7) << 4));
}

__launch_bounds__(256, 2)
__global__ void gate_kernel(const float* __restrict__ x, const float* __restrict__ W,
                            float* __restrict__ out) {
  // xh,xm,xl at 0,8K,16K ; wh,wm,wl at 24K(+0,8K,16K). Epilogue reuses front 16KB as fp32 logits.
  __shared__ __align__(16) char sm[48 * 1024];
  char* XT = sm;
  char* WT = sm + 24 * 1024;

  const int tid = threadIdx.x;
  const int r0 = blockIdx.x * MB;
  const int lane = tid & 63;
  const int wv = tid >> 6;        // 0..3
  const int rowgrp = wv >> 1;     // 32-row group
  const int colgrp = wv & 1;      // 32-expert group

  f32x4 xr[4], wr[4];             // prefetch registers (one chunk)

  auto load_chunk = [&](int c0) {
#pragma unroll
    for (int s = 0; s < 2; ++s) {
      int f = tid + s * 256;      // float8 id: row = f>>3, c8 = f&7
      int row = f >> 3, c8 = f & 7;
      const float* px = &x[(size_t)(r0 + row) * D_ + c0 + c8 * 8];
      xr[2 * s]     = *reinterpret_cast<const f32x4*>(px);
      xr[2 * s + 1] = *reinterpret_cast<const f32x4*>(px + 4);
      const float* pw = &W[(size_t)row * D_ + c0 + c8 * 8];
      wr[2 * s]     = *reinterpret_cast<const f32x4*>(pw);
      wr[2 * s + 1] = *reinterpret_cast<const f32x4*>(pw + 4);
    }
  };

  auto store_chunk = [&]() {
#pragma unroll
    for (int s = 0; s < 2; ++s) {
      int f = tid + s * 256;
      int row = f >> 3, c8 = f & 7;
      int off = swz(row, c8 * 16);
      {
        u16x8 h, m, l;
#pragma unroll
        for (int i = 0; i < 8; ++i) {
          float v = (i < 4) ? xr[2 * s][i] : xr[2 * s + 1][i - 4];
          u16 hh = f2bf(v);  float r1 = v - bf2f(hh);   // exact
          u16 mm = f2bf(r1); float r2 = r1 - bf2f(mm);  // exact
          u16 ll = f2bf(r2);
          h[i] = hh; m[i] = mm; l[i] = ll;
        }
        *reinterpret_cast<u16x8*>(XT + off)         = h;
        *reinterpret_cast<u16x8*>(XT + 8192 + off)  = m;
        *reinterpret_cast<u16x8*>(XT + 16384 + off) = l;
      }
      {
        u16x8 h, m, l;
#pragma unroll
        for (int i = 0; i < 8; ++i) {
          float v = (i < 4) ? wr[2 * s][i] : wr[2 * s + 1][i - 4];
          u16 hh = f2bf(v);  float r1 = v - bf2f(hh);
          u16 mm = f2bf(r1); float r2 = r1 - bf2f(mm);
          u16 ll = f2bf(r2);
          h[i] = hh; m[i] = mm; l[i] = ll;
        }
        *reinterpret_cast<u16x8*>(WT + off)         = h;
        *reinterpret_cast<u16x8*>(WT + 8192 + off)  = m;
        *reinterpret_cast<u16x8*>(WT + 16384 + off) = l;
      }
    }
  };

  f32x4 acc[2][2] = {};

  load_chunk(0);
  for (int ch = 0; ch < NCH; ++ch) {
    __syncthreads();              // prior chunk's LDS reads complete
    store_chunk();                // cvt + ds_write (compiler waits vmcnt)
    __syncthreads();
    if (ch + 1 < NCH) load_chunk((ch + 1) * DK);  // issue early: hide under MFMA

#pragma unroll
    for (int ks = 0; ks < 2; ++ks) {
      const int kb = ks * 64 + (lane >> 4) * 16;  // byte offset of this lane's 8-k group
      bf16x8 bh[2], bm[2], bl[2];
#pragma unroll
      for (int nf = 0; nf < 2; ++nf) {
        int e = colgrp * 32 + nf * 16 + (lane & 15);
        int off = swz(e, kb);
        bh[nf] = *reinterpret_cast<bf16x8*>(WT + off);
        bm[nf] = *reinterpret_cast<bf16x8*>(WT + 8192 + off);
        bl[nf] = *reinterpret_cast<bf16x8*>(WT + 16384 + off);
      }
#pragma unroll
      for (int mf = 0; mf < 2; ++mf) {
        int r = rowgrp * 32 + mf * 16 + (lane & 15);
        int off = swz(r, kb);
        bf16x8 ah = *reinterpret_cast<bf16x8*>(XT + off);
        bf16x8 am = *reinterpret_cast<bf16x8*>(XT + 8192 + off);
        bf16x8 al = *reinterpret_cast<bf16x8*>(XT + 16384 + off);
#pragma unroll
        for (int nf = 0; nf < 2; ++nf) {  // smallest terms first
          acc[mf][nf] = __builtin_amdgcn_mfma_f32_16x16x32_bf16(al, bh[nf], acc[mf][nf], 0, 0, 0);
          acc[mf][nf] = __builtin_amdgcn_mfma_f32_16x16x32_bf16(am, bm[nf], acc[mf][nf], 0, 0, 0);
          acc[mf][nf] = __builtin_amdgcn_mfma_f32_16x16x32_bf16(ah, bl[nf], acc[mf][nf], 0, 0, 0);
          acc[mf][nf] = __builtin_amdgcn_mfma_f32_16x16x32_bf16(am, bh[nf], acc[mf][nf], 0, 0, 0);
          acc[mf][nf] = __builtin_amdgcn_mfma_f32_16x16x32_bf16(ah, bm[nf], acc[mf][nf], 0, 0, 0);
          acc[mf][nf] = __builtin_amdgcn_mfma_f32_16x16x32_bf16(ah, bh[nf], acc[mf][nf], 0, 0, 0);
        }
      }
    }
  }

  // dump logits (C/D layout: col = lane&15, row = (lane>>4)*4 + reg) to LDS fp32 [64][64]
  __syncthreads();
  float* LGT = (float*)sm;
#pragma unroll
  for (int mf = 0; mf < 2; ++mf)
#pragma unroll
    for (int nf = 0; nf < 2; ++nf)
#pragma unroll
      for (int j = 0; j < 4; ++j) {
        int r = rowgrp * 32 + mf * 16 + (lane >> 4) * 4 + j;
        int e = colgrp * 32 + nf * 16 + (lane & 15);
        LGT[r * 64 + e] = acc[mf][nf][j];
      }
  __syncthreads();

  // top-k epilogue (verified in R1): 4 waves x 16 rows, lane = expert
  float* outI = out;
  float* outW = out + (size_t)T_ * KSEL;
  for (int rr = 0; rr < 16; ++rr) {
    const int r = wv * 16 + rr;
    const float lg = LGT[r * 64 + lane];
    float m = lg;
#pragma unroll
    for (int off = 32; off; off >>= 1) m = fmaxf(m, __shfl_xor(m, off, 64));
    const float p = expf(lg - m);
    float ssum = p;
#pragma unroll
    for (int off = 32; off; off >>= 1) ssum += __shfl_xor(ssum, off, 64);
    float prob = p / ssum;

    const int rg = r0 + r;
#pragma unroll
    for (int kk = 0; kk < KSEL; ++kk) {
      float v = prob; int idx = lane;
#pragma unroll
      for (int off = 32; off; off >>= 1) {
        float ov = __shfl_xor(v, off, 64);
        int oi = __shfl_xor(idx, off, 64);
        if (ov > v || (ov == v && oi < idx)) { v = ov; idx = oi; }
      }
      const float wsel = __shfl(lg, idx, 64);
      if (lane == 0) {
        outI[(size_t)rg * KSEL + kk] = (float)idx;
        outW[(size_t)rg * KSEL + kk] = wsel * ROUTE_SCALE_;
      }
      if (lane == idx) prob = -1.0f;
    }
  }
}

extern "C" void kernel_launch(void* const* d_in, const int* in_sizes, int n_in,
                              void* d_out, int out_size, void* d_ws, size_t ws_size,
                              hipStream_t stream) {
  const float* x = (const float*)d_in[0];
  const float* W = (const float*)d_in[1];
  float* out = (float*)d_out;
  gate_kernel<<<dim3(T_ / MB), dim3(256), 0, stream>>>(x, W, out);
}